// Round 6
// baseline (383.823 us; speedup 1.0000x reference)
//
#include <hip/hip_runtime.h>
#include <hip/hip_bf16.h>

// ---------- types ----------
typedef unsigned short bfu;                                        // bf16 bit-pattern storage
typedef short          bf16x8 __attribute__((ext_vector_type(8))); // MFMA A/B frag (4 VGPRs)
typedef float          floatx4 __attribute__((ext_vector_type(4)));// MFMA C/D frag
typedef unsigned short bfu4 __attribute__((ext_vector_type(4)));   // 8B packed store
typedef unsigned int   u32x2 __attribute__((ext_vector_type(2)));  // 8B LDS write

__device__ __forceinline__ bfu f2bf(float f) {
    __hip_bfloat16 h = __float2bfloat16(f);   // RNE
    return __builtin_bit_cast(unsigned short, h);
}

// async global->LDS, 16B per lane; lds base must be wave-uniform (HW adds lane*16)
__device__ __forceinline__ void glds16(const bfu* g, bfu* l) {
    __builtin_amdgcn_global_load_lds(
        (const __attribute__((address_space(1))) unsigned int*)g,
        (__attribute__((address_space(3))) unsigned int*)l, 16, 0, 0);
}

// ---------- problem constants ----------
#define BATCH 2
#define SEQ   2048
#define DM    2048
#define NH    16
#define DKH   128
#define SCALE 0.08838834764831845f   // 1/sqrt(128)

// =====================================================================
// convert x (f32) -> xb (bf16), 4 elems/thread
// =====================================================================
__global__ __launch_bounds__(256)
void cvt_x(const float* __restrict__ x, bfu* __restrict__ xb, int n) {
    const int i = (blockIdx.x * 256 + threadIdx.x) * 4;
    if (i >= n) return;
    const float4 v = *(const float4*)(x + i);
    bfu4 p; p[0] = f2bf(v.x); p[1] = f2bf(v.y); p[2] = f2bf(v.z); p[3] = f2bf(v.w);
    *(bfu4*)(xb + i) = p;
}

// =====================================================================
// vectorized 64x64 transpose+convert tile helper (float4 load, LDS
// [64][65] f32, bfu4 packed store -- 2-way banks both phases = free)
// =====================================================================
__device__ __forceinline__ void t64(const float* __restrict__ src,
                                    bfu* __restrict__ dst,
                                    int C, int r0, int c0, float s,
                                    float (*tile)[65]) {
    const int t  = threadIdx.x;
    const int lr = t >> 4;             // 0..15
    const int lc = (t & 15) * 4;       // 0,4,...,60
    #pragma unroll
    for (int pp = 0; pp < 4; pp++) {
        const float4 v = *(const float4*)(src + (size_t)(r0 + pp*16 + lr) * C + c0 + lc);
        tile[pp*16 + lr][lc + 0] = v.x;
        tile[pp*16 + lr][lc + 1] = v.y;
        tile[pp*16 + lr][lc + 2] = v.z;
        tile[pp*16 + lr][lc + 3] = v.w;
    }
    __syncthreads();
    const int rc = t & 15;             // 4-row chunk along r
    const int cb = t >> 4;             // 0..15
    #pragma unroll
    for (int pp = 0; pp < 4; pp++) {
        const int c = pp*16 + cb;
        bfu4 pk;
        #pragma unroll
        for (int j = 0; j < 4; j++) pk[j] = f2bf(tile[rc*4 + j][c] * s);
        *(bfu4*)(dst + (size_t)(c0 + c) * DM + r0 + rc*4) = pk;
    }
}

// fused Q/K/V weight transpose+convert: grid (2, 32, 48), block 256
__global__ __launch_bounds__(256)
void tcvt_qkv64(const float* __restrict__ WQ, const float* __restrict__ WK,
                const float* __restrict__ WV,
                bfu* __restrict__ WtQ, bfu* __restrict__ WtK, bfu* __restrict__ WtV) {
    __shared__ float tile[64][65];
    const int z = blockIdx.z;
    const int p = z >> 4, h = z & 15;
    const float* src = ((p == 0) ? WQ : (p == 1) ? WK : WV) + (size_t)h * DM * DKH;
    bfu*         dst = ((p == 0) ? WtQ : (p == 1) ? WtK : WtV) + (size_t)h * DKH * DM;
    const float  s   = (p == 0) ? SCALE : 1.0f;
    t64(src, dst, DKH, blockIdx.y * 64, blockIdx.x * 64, s, tile);
}

// WO transpose+convert: [2048(hk)][2048(d)] -> [d][hk].  grid (32,32)
__global__ __launch_bounds__(256)
void tcvt_wo64(const float* __restrict__ WO, bfu* __restrict__ WtO) {
    __shared__ float tile[64][65];
    t64(WO, WtO, DM, blockIdx.y * 64, blockIdx.x * 64, 1.0f, tile);
}

// =====================================================================
// 8-phase 256x256 GEMM helpers (T2 st_16x32 swizzle, T3/T4 counted vmcnt,
// T5 setprio).
// =====================================================================
__device__ __forceinline__ void stg_half(const bfu* gbase, bfu* slot,
                                         int wave, int lane, int csw) {
    #pragma unroll
    for (int l = 0; l < 2; l++) {
        const int j = l * 8 + wave;                         // wave-issue id 0..15
        glds16(gbase + (size_t)((j >> 1) * 16 + (lane >> 2)) * DM
                     + (j & 1) * 32 + csw,
               slot + j * 512);
    }
}

__device__ __forceinline__ void ld_b8(bf16x8 (&bv)[4][2], const bfu* slot, int rdo) {
    #pragma unroll
    for (int n = 0; n < 4; n++)
        #pragma unroll
        for (int ks = 0; ks < 2; ks++)
            bv[n][ks] = *(const bf16x8*)&slot[(n * 2 + ks) * 512 + rdo];
}

__device__ __forceinline__ void ld_a8(bf16x8 (&af)[4][2], const bfu* slot, int rdo) {
    #pragma unroll
    for (int m = 0; m < 4; m++)
        #pragma unroll
        for (int ks = 0; ks < 2; ks++)
            af[m][ks] = *(const bf16x8*)&slot[(m * 2 + ks) * 512 + rdo];
}

template<int MH, int NHALF>
__device__ __forceinline__ void mfma16(floatx4 (&acc)[8][4],
                                       const bf16x8 (&af)[4][2],
                                       const bf16x8 (&bv)[4][2]) {
    __builtin_amdgcn_s_setprio(1);
    #pragma unroll
    for (int m = 0; m < 4; m++)
        #pragma unroll
        for (int n = 0; n < 2; n++)
            #pragma unroll
            for (int ks = 0; ks < 2; ks++)
                acc[MH*4 + m][NHALF*2 + n] =
                    __builtin_amdgcn_mfma_f32_16x16x32_bf16(
                        af[m][ks], bv[NHALF*2 + n][ks],
                        acc[MH*4 + m][NHALF*2 + n], 0, 0, 0);
    __builtin_amdgcn_s_setprio(0);
}

#define BARW()                                                      \
    __builtin_amdgcn_s_barrier();                                   \
    asm volatile("s_waitcnt lgkmcnt(0)" ::: "memory");              \
    __builtin_amdgcn_sched_barrier(0)

// =====================================================================
// Q+K projection, 256^2 8-phase: grid (16, 16) = EXACTLY 256 blocks
// =====================================================================
__global__ __launch_bounds__(512, 2)
void proj_qk8(const bfu* __restrict__ xb,
              const bfu* __restrict__ WtQ, const bfu* __restrict__ WtK,
              const float* __restrict__ bQ, const float* __restrict__ bK,
              bfu* __restrict__ Qall, bfu* __restrict__ Kall) {
    __shared__ __align__(16) bfu As[2][2][8192];   // [buf][half][128*64]
    __shared__ __align__(16) bfu Bs[2][2][8192];

    const int p = blockIdx.y >> 3;
    const bfu*   Wt   = (p == 0) ? WtQ : WtK;
    const float* bias = (p == 0) ? bQ  : bK;
    const float  bscale = (p == 0) ? SCALE : 1.0f;

    const int tid  = threadIdx.x;
    const int lane = tid & 63;
    const int wave = tid >> 6;
    const int lrow = lane & 15;
    const int quad = lane >> 4;
    const int wr   = wave >> 2;            // 0..1 : M half (128 rows)
    const int wc   = wave & 3;             // 0..3 : N quarter (64 cols)
    const size_t m0 = (size_t)blockIdx.x * 256;
    const int    n0 = (int)(blockIdx.y & 7) * 256;

    const int csw = ((lane & 3) * 8) ^ ((lane & 32) ? 16 : 0);
    const int rdo = lrow * 32 + ((quad * 8) ^ ((lrow & 8) ? 16 : 0));

    const bfu* Ab = xb + m0 * DM;
    const bfu* Bb = Wt + (size_t)n0 * DM;

    floatx4 acc[8][4] = {};
    bf16x8 af[4][2], bv[4][2];

#define STAGE_A(tau, h)                                                     \
    if ((tau) < 32) stg_half(Ab + (size_t)((h) * 128) * DM + (tau) * 64,    \
                             &As[(tau) & 1][h][0], wave, lane, csw)
#define STAGE_B(tau, h)                                                     \
    if ((tau) < 32) stg_half(Bb + (size_t)((h) * 128) * DM + (tau) * 64,    \
                             &Bs[(tau) & 1][h][0], wave, lane, csw)

    // ---- prologue: 7 half-tiles (K-tile 0 + 3/4 of K-tile 1) ----
    STAGE_B(0, 0); STAGE_B(0, 1); STAGE_A(0, 0); STAGE_A(0, 1);
    STAGE_B(1, 0); STAGE_B(1, 1); STAGE_A(1, 0);
    asm volatile("s_waitcnt vmcnt(6)" ::: "memory");
    __builtin_amdgcn_s_barrier();

    #pragma unroll 1
    for (int i = 0; i < 16; i++) {
        const int t0 = 2 * i;
        // ======== K-tile t0 (buf 0) ========
        ld_b8(bv, &Bs[0][wc >> 1][(wc & 1) * 4096], rdo);
        ld_a8(af, &As[0][wr][0], rdo);
        STAGE_A(t0 + 1, 1);
        BARW();
        mfma16<0, 0>(acc, af, bv);
        __builtin_amdgcn_s_barrier();
        STAGE_B(t0 + 2, 0);
        BARW();
        mfma16<0, 1>(acc, af, bv);
        __builtin_amdgcn_s_barrier();
        ld_a8(af, &As[0][wr][4096], rdo);
        STAGE_B(t0 + 2, 1);
        BARW();
        mfma16<1, 0>(acc, af, bv);
        __builtin_amdgcn_s_barrier();
        STAGE_A(t0 + 2, 0);
        BARW();
        mfma16<1, 1>(acc, af, bv);
        if (i == 15) asm volatile("s_waitcnt vmcnt(0)" ::: "memory");
        else         asm volatile("s_waitcnt vmcnt(6)" ::: "memory");
        __builtin_amdgcn_s_barrier();
        // ======== K-tile t0+1 (buf 1) ========
        ld_b8(bv, &Bs[1][wc >> 1][(wc & 1) * 4096], rdo);
        ld_a8(af, &As[1][wr][0], rdo);
        STAGE_A(t0 + 2, 1);
        BARW();
        mfma16<0, 0>(acc, af, bv);
        __builtin_amdgcn_s_barrier();
        STAGE_B(t0 + 3, 0);
        BARW();
        mfma16<0, 1>(acc, af, bv);
        __builtin_amdgcn_s_barrier();
        ld_a8(af, &As[1][wr][4096], rdo);
        STAGE_B(t0 + 3, 1);
        BARW();
        mfma16<1, 0>(acc, af, bv);
        __builtin_amdgcn_s_barrier();
        STAGE_A(t0 + 3, 0);
        BARW();
        mfma16<1, 1>(acc, af, bv);
        if (i < 15) asm volatile("s_waitcnt vmcnt(6)" ::: "memory");
        __builtin_amdgcn_s_barrier();
    }
#undef STAGE_A
#undef STAGE_B

    // ---- epilogue (C/D: col = lane&15 -> n, row = quad*4+r -> m) ----
    bfu* Out = (p == 0) ? Qall : Kall;
    #pragma unroll
    for (int m = 0; m < 8; m++) {
        #pragma unroll
        for (int n = 0; n < 4; n++) {
            const int gn = n0 + wc * 64 + n * 16 + lrow;
            const float bvv = bias[gn] * bscale;
            #pragma unroll
            for (int r = 0; r < 4; r++) {
                const size_t gm = m0 + wr * 128 + m * 16 + quad * 4 + r;
                Out[gm * DM + gn] = f2bf(acc[m][n][r] + bvv);
            }
        }
    }
}

// =====================================================================
// V projection, 2-phase 128^2 (m97-style): Vt[b][h][dk][s] epilogue.
// grid (32,16), block 256
// =====================================================================
__global__ __launch_bounds__(256)
void proj_v(const bfu* __restrict__ xb, const bfu* __restrict__ WtV,
            const float* __restrict__ bV, bfu* __restrict__ Vt) {
    __shared__ bfu As[128 * 32];
    __shared__ bfu Bs[128 * 32];
    const int tid  = threadIdx.x;
    const int lane = tid & 63;
    const int wave = tid >> 6;
    const int lrow = lane & 15;
    const int quad = lane >> 4;
    const int mw = (wave & 1) * 64;
    const int nw = (wave >> 1) * 64;
    const size_t m0 = (size_t)blockIdx.x * 128;
    const size_t n0 = (size_t)blockIdx.y * 128;
    const int rowb = lane >> 2;          // 16-row group offset
    const int colb = (lane & 3) * 8;     // k-offset (elems)

    floatx4 acc[4][4] = {};

    for (int k0 = 0; k0 < DM; k0 += 32) {
        __syncthreads();
        #pragma unroll
        for (int i = 0; i < 2; i++) {
            const int rg = wave * 2 + i;    // 0..7 : 16-row groups
            glds16(xb  + (m0 + rg*16 + rowb) * DM + k0 + colb, &As[rg * 512]);
            glds16(WtV + (n0 + rg*16 + rowb) * DM + k0 + colb, &Bs[rg * 512]);
        }
        __syncthreads();
        bf16x8 af[4], bfr[4];
        #pragma unroll
        for (int t = 0; t < 4; t++) {
            af[t]  = *(const bf16x8*)&As[(mw + t*16 + lrow) * 32 + quad * 8];
            bfr[t] = *(const bf16x8*)&Bs[(nw + t*16 + lrow) * 32 + quad * 8];
        }
        #pragma unroll
        for (int mt = 0; mt < 4; mt++)
            #pragma unroll
            for (int nt = 0; nt < 4; nt++)
                acc[mt][nt] = __builtin_amdgcn_mfma_f32_16x16x32_bf16(
                                  af[mt], bfr[nt], acc[mt][nt], 0, 0, 0);
    }

    // transposed epilogue -> Vt[b][h][dk][s]
    #pragma unroll
    for (int mt = 0; mt < 4; mt++) {
        #pragma unroll
        for (int nt = 0; nt < 4; nt++) {
            const int nl = (int)n0 + nw + nt*16 + lrow;
            const float bvv = bV[nl];
            const size_t gm0 = m0 + mw + mt*16 + quad*4;   // 4 consecutive s rows
            const int b = (int)(gm0 >> 11), s = (int)(gm0 & 2047);
            bfu4 pk;
            #pragma unroll
            for (int r = 0; r < 4; r++) pk[r] = f2bf(acc[mt][nt][r] + bvv);
            *(bfu4*)&Vt[((size_t)(b * NH + (nl >> 7)) * DKH + (nl & 127)) * SEQ + s] = pk;
        }
    }
}

// =====================================================================
// causal flash attention, 64-key tiles, swapped QK^T, swizzled K/V LDS.
// NEW: QBLK=32 q rows per wave (2 q-groups share every K/V fragment
// read -> LDS traffic per FLOP halves; was the bottleneck: 34 ds_read
// per 32 MFMA).  Block = 128 q rows, 4 waves.  grid (32 hb, 16 qt'),
// block 256.  LDS: Ks 16K + Vs 16K + Ps[4][32][72] 18K = 50 KB
// -> 3 blocks/CU; VGPR capped 170 via launch_bounds(256,3).
// =====================================================================
__global__ __launch_bounds__(256, 3)
void flash_attn(const bfu* __restrict__ Q, const bfu* __restrict__ K,
                const bfu* __restrict__ Vt, bfu* __restrict__ Z) {
    __shared__ bfu Ks[4][64][32];    // [kc][key][32 k-elems] : 16 KB
    __shared__ bfu Vs[2][128][32];   // [s-half][dk][32 s]    : 16 KB
    __shared__ bfu Ps[4][32][72];    // per wave [q][64 s + 8 pad] : 18 KB

    const int tid  = threadIdx.x;
    const int lane = tid & 63;
    const int wave = tid >> 6;
    const int lrow = lane & 15;
    const int quad = lane >> 4;
    const int hb = blockIdx.x;
    const int h = hb & 15, b = hb >> 4;
    const int qt = 15 - blockIdx.y;            // heavy blocks first
    const int q0w = qt * 128 + wave * 32;
    const int rowb = lane >> 2;
    // stage: inverse-swizzled global col (LDS row = lane>>2 -> row&8 = lane&32)
    const int csw  = ((lane & 3) * 8) ^ ((lane & 32) ? 16 : 0);
    // read: chunk selector XOR (row&8 = lrow&8)
    const int rq0  = (quad * 8) ^ ((lrow & 8) ? 16 : 0);

    const bfu* Qrow0 = Q + (size_t)(b * SEQ + q0w + lrow) * DM + h * DKH;
    const bfu* Qrow1 = Qrow0 + (size_t)16 * DM;
    bf16x8 qf0[4], qf1[4];
    #pragma unroll
    for (int kc = 0; kc < 4; kc++) {
        qf0[kc] = *(const bf16x8*)(Qrow0 + kc*32 + quad*8);
        qf1[kc] = *(const bf16x8*)(Qrow1 + kc*32 + quad*8);
    }

    floatx4 z0[8] = {}, z1[8] = {};
    float l0 = 0.f, l1 = 0.f;
    const int qg0 = q0w + lrow;                // group-0 q row (swapped layout)
    const int qg1 = q0w + 16 + lrow;           // group-1 q row

    const bfu* Kb = K + (size_t)b * SEQ * DM + h * DKH;
    const bfu* Vb = Vt + (size_t)(b * NH + h) * DKH * SEQ;
    const int ntiles = 2 * (qt + 1);           // 64-key tiles, causal

    for (int it = 0; it < ntiles; it++) {
        const int s0 = it * 64;
        __syncthreads();                       // prior iter's LDS reads done
        #pragma unroll
        for (int i = 0; i < 8; i++) {
            const int chunk = wave * 8 + i;    // wave-uniform
            if (chunk < 16) {
                const int kc = chunk >> 2, kg = chunk & 3;
                glds16(Kb + (size_t)(s0 + kg*16 + rowb) * DM + kc*32 + csw,
                       &Ks[kc][kg*16][0]);
            } else {
                const int c2 = chunk - 16;
                const int sh = c2 >> 3, dg = c2 & 7;
                glds16(Vb + (size_t)(dg*16 + rowb) * SEQ + s0 + sh*32 + csw,
                       &Vs[sh][dg*16][0]);
            }
        }
        __syncthreads();                       // staged data visible

        // ---- S^T = K Q^T for both q-groups; each K frag feeds 2 MFMAs ----
        #pragma unroll
        for (int st = 0; st < 4; st++) {
            floatx4 a0 = {}, a1 = {};
            #pragma unroll
            for (int kc = 0; kc < 4; kc++) {
                bf16x8 kf = *(const bf16x8*)&Ks[kc][st*16 + lrow][rq0];
                a0 = __builtin_amdgcn_mfma_f32_16x16x32_bf16(kf, qf0[kc], a0, 0, 0, 0);
                a1 = __builtin_amdgcn_mfma_f32_16x16x32_bf16(kf, qf1[kc], a1, 0, 0, 0);
            }
            const int sbase = s0 + st*16 + quad*4;
            // group 0: mask + exp + packed b64 store
            {
                const float p0 = (sbase + 0 <= qg0) ? __expf(a0[0]) : 0.f;
                const float p1 = (sbase + 1 <= qg0) ? __expf(a0[1]) : 0.f;
                const float p2 = (sbase + 2 <= qg0) ? __expf(a0[2]) : 0.f;
                const float p3 = (sbase + 3 <= qg0) ? __expf(a0[3]) : 0.f;
                l0 += (p0 + p1) + (p2 + p3);
                u32x2 pk;
                pk[0] = (unsigned)f2bf(p0) | ((unsigned)f2bf(p1) << 16);
                pk[1] = (unsigned)f2bf(p2) | ((unsigned)f2bf(p3) << 16);
                *(u32x2*)&Ps[wave][lrow][st*16 + quad*4] = pk;
            }
            // group 1
            {
                const float p0 = (sbase + 0 <= qg1) ? __expf(a1[0]) : 0.f;
                const float p1 = (sbase + 1 <= qg1) ? __expf(a1[1]) : 0.f;
                const float p2 = (sbase + 2 <= qg1) ? __expf(a1[2]) : 0.f;
                const float p3 = (sbase + 3 <= qg1) ? __expf(a1[3]) : 0.f;
                l1 += (p0 + p1) + (p2 + p3);
                u32x2 pk;
                pk[0] = (unsigned)f2bf(p0) | ((unsigned)f2bf(p1) << 16);
                pk[1] = (unsigned)f2bf(p2) | ((unsigned)f2bf(p3) << 16);
                *(u32x2*)&Ps[wave][16 + lrow][st*16 + quad*4] = pk;
            }
        }

        // ---- O += P V ; each V frag feeds 2 MFMAs ----
        bf16x8 pf00 = *(const bf16x8*)&Ps[wave][lrow][quad*8];
        bf16x8 pf01 = *(const bf16x8*)&Ps[wave][lrow][32 + quad*8];
        bf16x8 pf10 = *(const bf16x8*)&Ps[wave][16 + lrow][quad*8];
        bf16x8 pf11 = *(const bf16x8*)&Ps[wave][16 + lrow][32 + quad*8];
        #pragma unroll
        for (int dt = 0; dt < 8; dt++) {
            bf16x8 v0 = *(const bf16x8*)&Vs[0][dt*16 + lrow][rq0];
            z0[dt] = __builtin_amdgcn_mfma_f32_16x16x32_bf16(pf00, v0, z0[dt], 0, 0, 0);
            z1[dt] = __builtin_amdgcn_mfma_f32_16x16x32_bf16(pf10, v0, z1[dt], 0, 0, 0);
            bf16x8 v1 = *(const bf16x8*)&Vs[1][dt*16 + lrow][rq0];
            z0[dt] = __builtin_amdgcn_mfma_f32_16x16x32_bf16(pf01, v1, z0[dt], 0, 0, 0);
            z1[dt] = __builtin_amdgcn_mfma_f32_16x16x32_bf16(pf11, v1, z1[dt], 0, 0, 0);
        }
    }

    // ---- final l reduce (per group) + normalize + store ----
    float L0 = l0, L1 = l1;
    L0 += __shfl_xor(L0, 16);  L0 += __shfl_xor(L0, 32);
    L1 += __shfl_xor(L1, 16);  L1 += __shfl_xor(L1, 32);
    float inv0[4], inv1[4];
    #pragma unroll
    for (int r = 0; r < 4; r++) {
        inv0[r] = 1.0f / __shfl(L0, quad*4 + r, 64);
        inv1[r] = 1.0f / __shfl(L1, quad*4 + r, 64);
    }
    #pragma unroll
    for (int dt = 0; dt < 8; dt++) {
        #pragma unroll
        for (int r = 0; r < 4; r++) {
            const int dk = dt*16 + lrow;
            const int qq0 = q0w + quad*4 + r;
            Z[(size_t)(b * SEQ + qq0) * DM + h * DKH + dk] = f2bf(z0[dt][r] * inv0[r]);
            const int qq1 = q0w + 16 + quad*4 + r;
            Z[(size_t)(b * SEQ + qq1) * DM + h * DKH + dk] = f2bf(z1[dt][r] * inv1[r]);
        }
    }
}

// =====================================================================
// output projection (m97-style): out_f32 = Zb * WtO^T + bO — unchanged
// =====================================================================
__global__ __launch_bounds__(256)
void out_gemm(const bfu* __restrict__ Zb, const bfu* __restrict__ WtO,
              const float* __restrict__ bO, float* out) {
    __shared__ bfu As[128 * 32];
    __shared__ bfu Bs[128 * 32];
    const int tid  = threadIdx.x;
    const int lane = tid & 63;
    const int wave = tid >> 6;
    const int lrow = lane & 15;
    const int quad = lane >> 4;
    const int mw = (wave & 1) * 64;
    const int nw = (wave >> 1) * 64;
    const size_t m0 = (size_t)blockIdx.x * 128;
    const size_t n0 = (size_t)blockIdx.y * 128;
    const int rowb = lane >> 2, colb = (lane & 3) * 8;

    floatx4 acc[4][4] = {};

    for (int k0 = 0; k0 < DM; k0 += 32) {
        __syncthreads();
        #pragma unroll
        for (int i = 0; i < 2; i++) {
            const int rg = wave * 2 + i;
            glds16(Zb  + (m0 + rg*16 + rowb) * DM + k0 + colb, &As[rg * 512]);
            glds16(WtO + (n0 + rg*16 + rowb) * DM + k0 + colb, &Bs[rg * 512]);
        }
        __syncthreads();
        bf16x8 af[4], bfr[4];
        #pragma unroll
        for (int t = 0; t < 4; t++) {
            af[t]  = *(const bf16x8*)&As[(mw + t*16 + lrow) * 32 + quad * 8];
            bfr[t] = *(const bf16x8*)&Bs[(nw + t*16 + lrow) * 32 + quad * 8];
        }
        #pragma unroll
        for (int mt = 0; mt < 4; mt++)
            #pragma unroll
            for (int nt = 0; nt < 4; nt++)
                acc[mt][nt] = __builtin_amdgcn_mfma_f32_16x16x32_bf16(
                                  af[mt], bfr[nt], acc[mt][nt], 0, 0, 0);
    }

    #pragma unroll
    for (int mt = 0; mt < 4; mt++) {
        #pragma unroll
        for (int nt = 0; nt < 4; nt++) {
            const size_t gn = n0 + nw + nt*16 + lrow;
            const float bv = bO[gn];
            #pragma unroll
            for (int r = 0; r < 4; r++) {
                const size_t gm = m0 + mw + mt*16 + quad*4 + r;
                out[gm * DM + gn] = acc[mt][nt][r] + bv;
            }
        }
    }
}

// =====================================================================
extern "C" void kernel_launch(void* const* d_in, const int* in_sizes, int n_in,
                              void* d_out, int out_size, void* d_ws, size_t ws_size,
                              hipStream_t stream) {
    const float* x  = (const float*)d_in[0];
    const float* WQ = (const float*)d_in[1];
    const float* bQ = (const float*)d_in[2];
    const float* WK = (const float*)d_in[3];
    const float* bK = (const float*)d_in[4];
    const float* WV = (const float*)d_in[5];
    const float* bV = (const float*)d_in[6];
    const float* WO = (const float*)d_in[7];
    const float* bO = (const float*)d_in[8];
    float* out = (float*)d_out;
    bfu* ws  = (bfu*)d_ws;
    bfu* dob = (bfu*)d_out;   // d_out doubles as scratch before out_gemm writes it

    // ws (64 MiB = 33.55M bfu):
    //   ws0: Qall [4096][2048]  -> after flash: WtO [2048][2048]
    //   ws1: Kall [4096][2048]
    //   ws2: Vt   [2][16][128][2048]
    //   ws3: WtV (4.19M) -> after proj: Zb [4096][2048]
    // d_out (16.78M bfu) as early scratch:
    //   xb  = dob[0 .. 8.39M)          (bf16 x)
    //   WtQ = dob[8.39M .. 12.58M)
    //   WtK = dob[12.58M .. 16.78M)
    bfu* Qall = ws;
    bfu* Kall = Qall + 8388608;
    bfu* Vt   = Kall + 8388608;
    bfu* Zb   = Vt   + 8388608;
    bfu* WtV  = Zb;                     // dead before flash writes Zb
    bfu* xb   = dob;
    bfu* WtQ  = dob + 8388608;
    bfu* WtK  = dob + 12582912;

    cvt_x<<<8192, 256, 0, stream>>>(x, xb, BATCH * SEQ * DM);

    // vectorized weight transposes (Q scaled by 1/sqrt(128))
    tcvt_qkv64<<<dim3(2, 32, 48), 256, 0, stream>>>(WQ, WK, WV, WtQ, WtK, WtV);

    // Q+K: one clean 256-block 8-phase round; V: 2-phase 128^2 (512 blocks)
    proj_qk8<<<dim3(16, 16), 512, 0, stream>>>(xb, WtQ, WtK, bQ, bK, Qall, Kall);
    proj_v<<<dim3(32, 16), 256, 0, stream>>>(xb, WtV, bV, Vt);

    flash_attn<<<dim3(32, 16), 256, 0, stream>>>(Qall, Kall, Vt, Zb);

    // Qall dead -> its region becomes WtO (vectorized transpose)
    tcvt_wo64<<<dim3(32, 32), 256, 0, stream>>>(WO, Qall);
    out_gemm<<<dim3(32, 16), 256, 0, stream>>>(Zb, Qall, bO, out);
}

// Round 7
// 365.025 us; speedup vs baseline: 1.0515x; 1.0515x over previous
//
#include <hip/hip_runtime.h>
#include <hip/hip_bf16.h>

// ---------- types ----------
typedef unsigned short bfu;                                        // bf16 bit-pattern storage
typedef short          bf16x8 __attribute__((ext_vector_type(8))); // MFMA A/B frag (4 VGPRs)
typedef float          floatx4 __attribute__((ext_vector_type(4)));// MFMA C/D frag
typedef unsigned short bfu4 __attribute__((ext_vector_type(4)));   // 8B packed store
typedef unsigned int   u32x2 __attribute__((ext_vector_type(2)));  // 8B LDS write

__device__ __forceinline__ bfu f2bf(float f) {
    __hip_bfloat16 h = __float2bfloat16(f);   // RNE
    return __builtin_bit_cast(unsigned short, h);
}

// async global->LDS, 16B per lane; lds base must be wave-uniform (HW adds lane*16)
__device__ __forceinline__ void glds16(const bfu* g, bfu* l) {
    __builtin_amdgcn_global_load_lds(
        (const __attribute__((address_space(1))) unsigned int*)g,
        (__attribute__((address_space(3))) unsigned int*)l, 16, 0, 0);
}

// ---------- problem constants ----------
#define BATCH 2
#define SEQ   2048
#define DM    2048
#define NH    16
#define DKH   128
#define SCALE 0.08838834764831845f   // 1/sqrt(128)

// =====================================================================
// convert x (f32) -> xb (bf16), 4 elems/thread
// =====================================================================
__global__ __launch_bounds__(256)
void cvt_x(const float* __restrict__ x, bfu* __restrict__ xb, int n) {
    const int i = (blockIdx.x * 256 + threadIdx.x) * 4;
    if (i >= n) return;
    const float4 v = *(const float4*)(x + i);
    bfu4 p; p[0] = f2bf(v.x); p[1] = f2bf(v.y); p[2] = f2bf(v.z); p[3] = f2bf(v.w);
    *(bfu4*)(xb + i) = p;
}

// =====================================================================
// vectorized 64x64 transpose+convert tile helper (float4 load, LDS
// [64][65] f32, bfu4 packed store -- 2-way banks both phases = free)
// =====================================================================
__device__ __forceinline__ void t64(const float* __restrict__ src,
                                    bfu* __restrict__ dst,
                                    int C, int r0, int c0, float s,
                                    float (*tile)[65]) {
    const int t  = threadIdx.x;
    const int lr = t >> 4;             // 0..15
    const int lc = (t & 15) * 4;       // 0,4,...,60
    #pragma unroll
    for (int pp = 0; pp < 4; pp++) {
        const float4 v = *(const float4*)(src + (size_t)(r0 + pp*16 + lr) * C + c0 + lc);
        tile[pp*16 + lr][lc + 0] = v.x;
        tile[pp*16 + lr][lc + 1] = v.y;
        tile[pp*16 + lr][lc + 2] = v.z;
        tile[pp*16 + lr][lc + 3] = v.w;
    }
    __syncthreads();
    const int rc = t & 15;             // 4-row chunk along r
    const int cb = t >> 4;             // 0..15
    #pragma unroll
    for (int pp = 0; pp < 4; pp++) {
        const int c = pp*16 + cb;
        bfu4 pk;
        #pragma unroll
        for (int j = 0; j < 4; j++) pk[j] = f2bf(tile[rc*4 + j][c] * s);
        *(bfu4*)(dst + (size_t)(c0 + c) * DM + r0 + rc*4) = pk;
    }
}

// fused Q/K/V weight transpose+convert: grid (2, 32, 48), block 256
__global__ __launch_bounds__(256)
void tcvt_qkv64(const float* __restrict__ WQ, const float* __restrict__ WK,
                const float* __restrict__ WV,
                bfu* __restrict__ WtQ, bfu* __restrict__ WtK, bfu* __restrict__ WtV) {
    __shared__ float tile[64][65];
    const int z = blockIdx.z;
    const int p = z >> 4, h = z & 15;
    const float* src = ((p == 0) ? WQ : (p == 1) ? WK : WV) + (size_t)h * DM * DKH;
    bfu*         dst = ((p == 0) ? WtQ : (p == 1) ? WtK : WtV) + (size_t)h * DKH * DM;
    const float  s   = (p == 0) ? SCALE : 1.0f;
    t64(src, dst, DKH, blockIdx.y * 64, blockIdx.x * 64, s, tile);
}

// WO transpose+convert: [2048(hk)][2048(d)] -> [d][hk].  grid (32,32)
__global__ __launch_bounds__(256)
void tcvt_wo64(const float* __restrict__ WO, bfu* __restrict__ WtO) {
    __shared__ float tile[64][65];
    t64(WO, WtO, DM, blockIdx.y * 64, blockIdx.x * 64, 1.0f, tile);
}

// =====================================================================
// 8-phase 256x256 GEMM helpers (T2 st_16x32 swizzle, T3/T4 counted vmcnt,
// T5 setprio).
// =====================================================================
__device__ __forceinline__ void stg_half(const bfu* gbase, bfu* slot,
                                         int wave, int lane, int csw) {
    #pragma unroll
    for (int l = 0; l < 2; l++) {
        const int j = l * 8 + wave;                         // wave-issue id 0..15
        glds16(gbase + (size_t)((j >> 1) * 16 + (lane >> 2)) * DM
                     + (j & 1) * 32 + csw,
               slot + j * 512);
    }
}

__device__ __forceinline__ void ld_b8(bf16x8 (&bv)[4][2], const bfu* slot, int rdo) {
    #pragma unroll
    for (int n = 0; n < 4; n++)
        #pragma unroll
        for (int ks = 0; ks < 2; ks++)
            bv[n][ks] = *(const bf16x8*)&slot[(n * 2 + ks) * 512 + rdo];
}

__device__ __forceinline__ void ld_a8(bf16x8 (&af)[4][2], const bfu* slot, int rdo) {
    #pragma unroll
    for (int m = 0; m < 4; m++)
        #pragma unroll
        for (int ks = 0; ks < 2; ks++)
            af[m][ks] = *(const bf16x8*)&slot[(m * 2 + ks) * 512 + rdo];
}

template<int MH, int NHALF>
__device__ __forceinline__ void mfma16(floatx4 (&acc)[8][4],
                                       const bf16x8 (&af)[4][2],
                                       const bf16x8 (&bv)[4][2]) {
    __builtin_amdgcn_s_setprio(1);
    #pragma unroll
    for (int m = 0; m < 4; m++)
        #pragma unroll
        for (int n = 0; n < 2; n++)
            #pragma unroll
            for (int ks = 0; ks < 2; ks++)
                acc[MH*4 + m][NHALF*2 + n] =
                    __builtin_amdgcn_mfma_f32_16x16x32_bf16(
                        af[m][ks], bv[NHALF*2 + n][ks],
                        acc[MH*4 + m][NHALF*2 + n], 0, 0, 0);
    __builtin_amdgcn_s_setprio(0);
}

#define BARW()                                                      \
    __builtin_amdgcn_s_barrier();                                   \
    asm volatile("s_waitcnt lgkmcnt(0)" ::: "memory");              \
    __builtin_amdgcn_sched_barrier(0)

// =====================================================================
// Q+K projection, 256^2 8-phase: grid (16, 16) = EXACTLY 256 blocks
// =====================================================================
__global__ __launch_bounds__(512, 2)
void proj_qk8(const bfu* __restrict__ xb,
              const bfu* __restrict__ WtQ, const bfu* __restrict__ WtK,
              const float* __restrict__ bQ, const float* __restrict__ bK,
              bfu* __restrict__ Qall, bfu* __restrict__ Kall) {
    __shared__ __align__(16) bfu As[2][2][8192];   // [buf][half][128*64]
    __shared__ __align__(16) bfu Bs[2][2][8192];

    const int p = blockIdx.y >> 3;
    const bfu*   Wt   = (p == 0) ? WtQ : WtK;
    const float* bias = (p == 0) ? bQ  : bK;
    const float  bscale = (p == 0) ? SCALE : 1.0f;

    const int tid  = threadIdx.x;
    const int lane = tid & 63;
    const int wave = tid >> 6;
    const int lrow = lane & 15;
    const int quad = lane >> 4;
    const int wr   = wave >> 2;            // 0..1 : M half (128 rows)
    const int wc   = wave & 3;             // 0..3 : N quarter (64 cols)
    const size_t m0 = (size_t)blockIdx.x * 256;
    const int    n0 = (int)(blockIdx.y & 7) * 256;

    const int csw = ((lane & 3) * 8) ^ ((lane & 32) ? 16 : 0);
    const int rdo = lrow * 32 + ((quad * 8) ^ ((lrow & 8) ? 16 : 0));

    const bfu* Ab = xb + m0 * DM;
    const bfu* Bb = Wt + (size_t)n0 * DM;

    floatx4 acc[8][4] = {};
    bf16x8 af[4][2], bv[4][2];

#define STAGE_A(tau, h)                                                     \
    if ((tau) < 32) stg_half(Ab + (size_t)((h) * 128) * DM + (tau) * 64,    \
                             &As[(tau) & 1][h][0], wave, lane, csw)
#define STAGE_B(tau, h)                                                     \
    if ((tau) < 32) stg_half(Bb + (size_t)((h) * 128) * DM + (tau) * 64,    \
                             &Bs[(tau) & 1][h][0], wave, lane, csw)

    // ---- prologue: 7 half-tiles (K-tile 0 + 3/4 of K-tile 1) ----
    STAGE_B(0, 0); STAGE_B(0, 1); STAGE_A(0, 0); STAGE_A(0, 1);
    STAGE_B(1, 0); STAGE_B(1, 1); STAGE_A(1, 0);
    asm volatile("s_waitcnt vmcnt(6)" ::: "memory");
    __builtin_amdgcn_s_barrier();

    #pragma unroll 1
    for (int i = 0; i < 16; i++) {
        const int t0 = 2 * i;
        // ======== K-tile t0 (buf 0) ========
        ld_b8(bv, &Bs[0][wc >> 1][(wc & 1) * 4096], rdo);
        ld_a8(af, &As[0][wr][0], rdo);
        STAGE_A(t0 + 1, 1);
        BARW();
        mfma16<0, 0>(acc, af, bv);
        __builtin_amdgcn_s_barrier();
        STAGE_B(t0 + 2, 0);
        BARW();
        mfma16<0, 1>(acc, af, bv);
        __builtin_amdgcn_s_barrier();
        ld_a8(af, &As[0][wr][4096], rdo);
        STAGE_B(t0 + 2, 1);
        BARW();
        mfma16<1, 0>(acc, af, bv);
        __builtin_amdgcn_s_barrier();
        STAGE_A(t0 + 2, 0);
        BARW();
        mfma16<1, 1>(acc, af, bv);
        if (i == 15) asm volatile("s_waitcnt vmcnt(0)" ::: "memory");
        else         asm volatile("s_waitcnt vmcnt(6)" ::: "memory");
        __builtin_amdgcn_s_barrier();
        // ======== K-tile t0+1 (buf 1) ========
        ld_b8(bv, &Bs[1][wc >> 1][(wc & 1) * 4096], rdo);
        ld_a8(af, &As[1][wr][0], rdo);
        STAGE_A(t0 + 2, 1);
        BARW();
        mfma16<0, 0>(acc, af, bv);
        __builtin_amdgcn_s_barrier();
        STAGE_B(t0 + 3, 0);
        BARW();
        mfma16<0, 1>(acc, af, bv);
        __builtin_amdgcn_s_barrier();
        ld_a8(af, &As[1][wr][4096], rdo);
        STAGE_B(t0 + 3, 1);
        BARW();
        mfma16<1, 0>(acc, af, bv);
        __builtin_amdgcn_s_barrier();
        STAGE_A(t0 + 3, 0);
        BARW();
        mfma16<1, 1>(acc, af, bv);
        if (i < 15) asm volatile("s_waitcnt vmcnt(6)" ::: "memory");
        __builtin_amdgcn_s_barrier();
    }
#undef STAGE_A
#undef STAGE_B

    // ---- epilogue (C/D: col = lane&15 -> n, row = quad*4+r -> m) ----
    bfu* Out = (p == 0) ? Qall : Kall;
    #pragma unroll
    for (int m = 0; m < 8; m++) {
        #pragma unroll
        for (int n = 0; n < 4; n++) {
            const int gn = n0 + wc * 64 + n * 16 + lrow;
            const float bvv = bias[gn] * bscale;
            #pragma unroll
            for (int r = 0; r < 4; r++) {
                const size_t gm = m0 + wr * 128 + m * 16 + quad * 4 + r;
                Out[gm * DM + gn] = f2bf(acc[m][n][r] + bvv);
            }
        }
    }
}

// =====================================================================
// V projection, 2-phase 128^2 (m97-style): Vt[b][h][dk][s] epilogue.
// grid (32,16), block 256
// =====================================================================
__global__ __launch_bounds__(256)
void proj_v(const bfu* __restrict__ xb, const bfu* __restrict__ WtV,
            const float* __restrict__ bV, bfu* __restrict__ Vt) {
    __shared__ bfu As[128 * 32];
    __shared__ bfu Bs[128 * 32];
    const int tid  = threadIdx.x;
    const int lane = tid & 63;
    const int wave = tid >> 6;
    const int lrow = lane & 15;
    const int quad = lane >> 4;
    const int mw = (wave & 1) * 64;
    const int nw = (wave >> 1) * 64;
    const size_t m0 = (size_t)blockIdx.x * 128;
    const size_t n0 = (size_t)blockIdx.y * 128;
    const int rowb = lane >> 2;          // 16-row group offset
    const int colb = (lane & 3) * 8;     // k-offset (elems)

    floatx4 acc[4][4] = {};

    for (int k0 = 0; k0 < DM; k0 += 32) {
        __syncthreads();
        #pragma unroll
        for (int i = 0; i < 2; i++) {
            const int rg = wave * 2 + i;    // 0..7 : 16-row groups
            glds16(xb  + (m0 + rg*16 + rowb) * DM + k0 + colb, &As[rg * 512]);
            glds16(WtV + (n0 + rg*16 + rowb) * DM + k0 + colb, &Bs[rg * 512]);
        }
        __syncthreads();
        bf16x8 af[4], bfr[4];
        #pragma unroll
        for (int t = 0; t < 4; t++) {
            af[t]  = *(const bf16x8*)&As[(mw + t*16 + lrow) * 32 + quad * 8];
            bfr[t] = *(const bf16x8*)&Bs[(nw + t*16 + lrow) * 32 + quad * 8];
        }
        #pragma unroll
        for (int mt = 0; mt < 4; mt++)
            #pragma unroll
            for (int nt = 0; nt < 4; nt++)
                acc[mt][nt] = __builtin_amdgcn_mfma_f32_16x16x32_bf16(
                                  af[mt], bfr[nt], acc[mt][nt], 0, 0, 0);
    }

    // transposed epilogue -> Vt[b][h][dk][s]
    #pragma unroll
    for (int mt = 0; mt < 4; mt++) {
        #pragma unroll
        for (int nt = 0; nt < 4; nt++) {
            const int nl = (int)n0 + nw + nt*16 + lrow;
            const float bvv = bV[nl];
            const size_t gm0 = m0 + mw + mt*16 + quad*4;   // 4 consecutive s rows
            const int b = (int)(gm0 >> 11), s = (int)(gm0 & 2047);
            bfu4 pk;
            #pragma unroll
            for (int r = 0; r < 4; r++) pk[r] = f2bf(acc[mt][nt][r] + bvv);
            *(bfu4*)&Vt[((size_t)(b * NH + (nl >> 7)) * DKH + (nl & 127)) * SEQ + s] = pk;
        }
    }
}

// =====================================================================
// causal flash attention, 64-key tiles, swapped QK^T, swizzled K/V LDS.
// REVERT R6's QBLK=32 (occupancy 12.5% + VGPR spill regression).
// NEW: K/V tiles double-buffered (T3 minimum-2-phase recipe): stage
// tile t+1 into buf^1 BEFORE computing tile t; single vmcnt(0)+barrier
// per tile at the bottom -> HBM stage latency hides under the 32 MFMA
// + softmax of the current tile (was: serial stage->drain->compute).
// LDS 73 KB -> 2 blocks/CU (= measured R5 residency).
// grid (32 hb, 32 qt'), block 256
// =====================================================================
__global__ __launch_bounds__(256)
void flash_attn(const bfu* __restrict__ Q, const bfu* __restrict__ K,
                const bfu* __restrict__ Vt, bfu* __restrict__ Z) {
    __shared__ bfu Ks[2][4][64][32];   // [buf][kc][key][32 k-elems] : 32 KB
    __shared__ bfu Vs[2][2][128][32];  // [buf][s-half][dk][32 s]    : 32 KB
    __shared__ bfu Ps[4][16][72];      // per wave [q][64 s + 8 pad] : 9 KB

    const int tid  = threadIdx.x;
    const int lane = tid & 63;
    const int wave = tid >> 6;
    const int lrow = lane & 15;
    const int quad = lane >> 4;
    const int hb = blockIdx.x;
    const int h = hb & 15, b = hb >> 4;
    const int qt = 31 - blockIdx.y;            // heavy blocks first
    const int q0w = qt * 64 + wave * 16;
    const int rowb = lane >> 2;
    // stage: inverse-swizzled global col (LDS row = lane>>2 -> row&8 = lane&32)
    const int csw  = ((lane & 3) * 8) ^ ((lane & 32) ? 16 : 0);
    // read: chunk selector XOR (row&8 = lrow&8)
    const int rq0  = (quad * 8) ^ ((lrow & 8) ? 16 : 0);

    const bfu* Qrow = Q + (size_t)(b * SEQ + q0w + lrow) * DM + h * DKH;
    bf16x8 qf[4];
    #pragma unroll
    for (int kc = 0; kc < 4; kc++)
        qf[kc] = *(const bf16x8*)(Qrow + kc*32 + quad*8);

    floatx4 z[8] = {};
    float l_loc = 0.f;
    const int qg = q0w + lrow;                 // this lane's q row (swapped layout)

    const bfu* Kb = K + (size_t)b * SEQ * DM + h * DKH;
    const bfu* Vb = Vt + (size_t)(b * NH + h) * DKH * SEQ;
    const int ntiles = qt + 1;                 // 64-key tiles, causal

    // stage one 64-key tile (K 16 chunks + V^T 16 chunks) into buffer nb
    auto STAGE = [&](int nb, int s0) {
        #pragma unroll
        for (int i = 0; i < 8; i++) {
            const int chunk = wave * 8 + i;    // wave-uniform
            if (chunk < 16) {
                const int kc = chunk >> 2, kg = chunk & 3;
                glds16(Kb + (size_t)(s0 + kg*16 + rowb) * DM + kc*32 + csw,
                       &Ks[nb][kc][kg*16][0]);
            } else {
                const int c2 = chunk - 16;
                const int sh = c2 >> 3, dg = c2 & 7;
                glds16(Vb + (size_t)(dg*16 + rowb) * SEQ + s0 + sh*32 + csw,
                       &Vs[nb][sh][dg*16][0]);
            }
        }
    };

    // ---- prologue: tile 0 into buf 0 ----
    STAGE(0, 0);
    asm volatile("s_waitcnt vmcnt(0)" ::: "memory");
    __syncthreads();

    for (int it = 0; it < ntiles; it++) {
        const int cur = it & 1;
        // issue next tile's stage FIRST (overlaps with compute below);
        // safe: buf cur^1's readers finished before the prior barrier.
        if (it + 1 < ntiles) STAGE(cur ^ 1, (it + 1) * 64);
        const int s0 = it * 64;

        // ---- S^T = K Q^T : lane holds S[s=st*16+quad*4+r][q=lrow] ----
        floatx4 sc[4];
        #pragma unroll
        for (int st = 0; st < 4; st++) {
            floatx4 a = {};
            #pragma unroll
            for (int kc = 0; kc < 4; kc++) {
                bf16x8 kf = *(const bf16x8*)&Ks[cur][kc][st*16 + lrow][rq0];
                a = __builtin_amdgcn_mfma_f32_16x16x32_bf16(kf, qf[kc], a, 0, 0, 0);
            }
            sc[st] = a;
        }

        // ---- mask + exp + packed b64 store ----
        #pragma unroll
        for (int st = 0; st < 4; st++) {
            const int sbase = s0 + st*16 + quad*4;
            const float p0 = (sbase + 0 <= qg) ? __expf(sc[st][0]) : 0.f;
            const float p1 = (sbase + 1 <= qg) ? __expf(sc[st][1]) : 0.f;
            const float p2 = (sbase + 2 <= qg) ? __expf(sc[st][2]) : 0.f;
            const float p3 = (sbase + 3 <= qg) ? __expf(sc[st][3]) : 0.f;
            l_loc += (p0 + p1) + (p2 + p3);
            u32x2 pk;
            pk[0] = (unsigned)f2bf(p0) | ((unsigned)f2bf(p1) << 16);
            pk[1] = (unsigned)f2bf(p2) | ((unsigned)f2bf(p3) << 16);
            *(u32x2*)&Ps[wave][lrow][st*16 + quad*4] = pk;
        }

        // ---- O += P V ----
        bf16x8 pf0 = *(const bf16x8*)&Ps[wave][lrow][quad*8];
        bf16x8 pf1 = *(const bf16x8*)&Ps[wave][lrow][32 + quad*8];
        #pragma unroll
        for (int dt = 0; dt < 8; dt++) {
            bf16x8 v0 = *(const bf16x8*)&Vs[cur][0][dt*16 + lrow][rq0];
            z[dt] = __builtin_amdgcn_mfma_f32_16x16x32_bf16(pf0, v0, z[dt], 0, 0, 0);
            bf16x8 v1 = *(const bf16x8*)&Vs[cur][1][dt*16 + lrow][rq0];
            z[dt] = __builtin_amdgcn_mfma_f32_16x16x32_bf16(pf1, v1, z[dt], 0, 0, 0);
        }

        // next tile staged + all waves' reads of buf cur done
        asm volatile("s_waitcnt vmcnt(0)" ::: "memory");
        __syncthreads();
    }

    // ---- final l reduce + normalize + store ----
    float L = l_loc;
    L += __shfl_xor(L, 16);
    L += __shfl_xor(L, 32);
    float inv[4];
    #pragma unroll
    for (int r = 0; r < 4; r++)
        inv[r] = 1.0f / __shfl(L, quad*4 + r, 64);
    #pragma unroll
    for (int dt = 0; dt < 8; dt++) {
        #pragma unroll
        for (int r = 0; r < 4; r++) {
            const int qq = q0w + quad*4 + r;
            const int dk = dt*16 + lrow;
            Z[(size_t)(b * SEQ + qq) * DM + h * DKH + dk] = f2bf(z[dt][r] * inv[r]);
        }
    }
}

// =====================================================================
// output projection (m97-style): out_f32 = Zb * WtO^T + bO — unchanged
// =====================================================================
__global__ __launch_bounds__(256)
void out_gemm(const bfu* __restrict__ Zb, const bfu* __restrict__ WtO,
              const float* __restrict__ bO, float* out) {
    __shared__ bfu As[128 * 32];
    __shared__ bfu Bs[128 * 32];
    const int tid  = threadIdx.x;
    const int lane = tid & 63;
    const int wave = tid >> 6;
    const int lrow = lane & 15;
    const int quad = lane >> 4;
    const int mw = (wave & 1) * 64;
    const int nw = (wave >> 1) * 64;
    const size_t m0 = (size_t)blockIdx.x * 128;
    const size_t n0 = (size_t)blockIdx.y * 128;
    const int rowb = lane >> 2, colb = (lane & 3) * 8;

    floatx4 acc[4][4] = {};

    for (int k0 = 0; k0 < DM; k0 += 32) {
        __syncthreads();
        #pragma unroll
        for (int i = 0; i < 2; i++) {
            const int rg = wave * 2 + i;
            glds16(Zb  + (m0 + rg*16 + rowb) * DM + k0 + colb, &As[rg * 512]);
            glds16(WtO + (n0 + rg*16 + rowb) * DM + k0 + colb, &Bs[rg * 512]);
        }
        __syncthreads();
        bf16x8 af[4], bfr[4];
        #pragma unroll
        for (int t = 0; t < 4; t++) {
            af[t]  = *(const bf16x8*)&As[(mw + t*16 + lrow) * 32 + quad * 8];
            bfr[t] = *(const bf16x8*)&Bs[(nw + t*16 + lrow) * 32 + quad * 8];
        }
        #pragma unroll
        for (int mt = 0; mt < 4; mt++)
            #pragma unroll
            for (int nt = 0; nt < 4; nt++)
                acc[mt][nt] = __builtin_amdgcn_mfma_f32_16x16x32_bf16(
                                  af[mt], bfr[nt], acc[mt][nt], 0, 0, 0);
    }

    #pragma unroll
    for (int mt = 0; mt < 4; mt++) {
        #pragma unroll
        for (int nt = 0; nt < 4; nt++) {
            const size_t gn = n0 + nw + nt*16 + lrow;
            const float bv = bO[gn];
            #pragma unroll
            for (int r = 0; r < 4; r++) {
                const size_t gm = m0 + mw + mt*16 + quad*4 + r;
                out[gm * DM + gn] = acc[mt][nt][r] + bv;
            }
        }
    }
}

// =====================================================================
extern "C" void kernel_launch(void* const* d_in, const int* in_sizes, int n_in,
                              void* d_out, int out_size, void* d_ws, size_t ws_size,
                              hipStream_t stream) {
    const float* x  = (const float*)d_in[0];
    const float* WQ = (const float*)d_in[1];
    const float* bQ = (const float*)d_in[2];
    const float* WK = (const float*)d_in[3];
    const float* bK = (const float*)d_in[4];
    const float* WV = (const float*)d_in[5];
    const float* bV = (const float*)d_in[6];
    const float* WO = (const float*)d_in[7];
    const float* bO = (const float*)d_in[8];
    float* out = (float*)d_out;
    bfu* ws  = (bfu*)d_ws;
    bfu* dob = (bfu*)d_out;   // d_out doubles as scratch before out_gemm writes it

    // ws (64 MiB = 33.55M bfu):
    //   ws0: Qall [4096][2048]  -> after flash: WtO [2048][2048]
    //   ws1: Kall [4096][2048]
    //   ws2: Vt   [2][16][128][2048]
    //   ws3: WtV (4.19M) -> after proj: Zb [4096][2048]
    // d_out (16.78M bfu) as early scratch:
    //   xb  = dob[0 .. 8.39M)          (bf16 x)
    //   WtQ = dob[8.39M .. 12.58M)
    //   WtK = dob[12.58M .. 16.78M)
    bfu* Qall = ws;
    bfu* Kall = Qall + 8388608;
    bfu* Vt   = Kall + 8388608;
    bfu* Zb   = Vt   + 8388608;
    bfu* WtV  = Zb;                     // dead before flash writes Zb
    bfu* xb   = dob;
    bfu* WtQ  = dob + 8388608;
    bfu* WtK  = dob + 12582912;

    cvt_x<<<8192, 256, 0, stream>>>(x, xb, BATCH * SEQ * DM);

    // vectorized weight transposes (Q scaled by 1/sqrt(128))
    tcvt_qkv64<<<dim3(2, 32, 48), 256, 0, stream>>>(WQ, WK, WV, WtQ, WtK, WtV);

    // Q+K: one clean 256-block 8-phase round; V: 2-phase 128^2 (512 blocks)
    proj_qk8<<<dim3(16, 16), 512, 0, stream>>>(xb, WtQ, WtK, bQ, bK, Qall, Kall);
    proj_v<<<dim3(32, 16), 256, 0, stream>>>(xb, WtV, bV, Vt);

    flash_attn<<<dim3(32, 32), 256, 0, stream>>>(Qall, Kall, Vt, Zb);

    // Qall dead -> its region becomes WtO (vectorized transpose)
    tcvt_wo64<<<dim3(32, 32), 256, 0, stream>>>(WO, Qall);
    out_gemm<<<dim3(32, 16), 256, 0, stream>>>(Zb, Qall, bO, out);
}

// Round 8
// 360.605 us; speedup vs baseline: 1.0644x; 1.0123x over previous
//
#include <hip/hip_runtime.h>
#include <hip/hip_bf16.h>

// ---------- types ----------
typedef unsigned short bfu;                                        // bf16 bit-pattern storage
typedef short          bf16x8 __attribute__((ext_vector_type(8))); // MFMA A/B frag (4 VGPRs)
typedef float          floatx4 __attribute__((ext_vector_type(4)));// MFMA C/D frag
typedef unsigned short bfu4 __attribute__((ext_vector_type(4)));   // 8B packed store
typedef unsigned int   u32x2 __attribute__((ext_vector_type(2)));  // 8B LDS write

__device__ __forceinline__ bfu f2bf(float f) {
    __hip_bfloat16 h = __float2bfloat16(f);   // RNE
    return __builtin_bit_cast(unsigned short, h);
}

// hardware 2^x (no range reduction needed for exp2)
__device__ __forceinline__ float ex2(float x) {
#if __has_builtin(__builtin_amdgcn_exp2f)
    return __builtin_amdgcn_exp2f(x);
#else
    return exp2f(x);
#endif
}

// async global->LDS, 16B per lane; lds base must be wave-uniform (HW adds lane*16)
__device__ __forceinline__ void glds16(const bfu* g, bfu* l) {
    __builtin_amdgcn_global_load_lds(
        (const __attribute__((address_space(1))) unsigned int*)g,
        (__attribute__((address_space(3))) unsigned int*)l, 16, 0, 0);
}

// ---------- problem constants ----------
#define BATCH 2
#define SEQ   2048
#define DM    2048
#define NH    16
#define DKH   128
#define SCALE  0.08838834764831845f   // 1/sqrt(128)
#define SCALEQ 0.1275174245f          // log2(e)/sqrt(128): scores in log2 domain

// =====================================================================
// convert x (f32) -> xb (bf16), 4 elems/thread
// =====================================================================
__global__ __launch_bounds__(256)
void cvt_x(const float* __restrict__ x, bfu* __restrict__ xb, int n) {
    const int i = (blockIdx.x * 256 + threadIdx.x) * 4;
    if (i >= n) return;
    const float4 v = *(const float4*)(x + i);
    bfu4 p; p[0] = f2bf(v.x); p[1] = f2bf(v.y); p[2] = f2bf(v.z); p[3] = f2bf(v.w);
    *(bfu4*)(xb + i) = p;
}

// =====================================================================
// vectorized 64x64 transpose+convert tile helper (float4 load, LDS
// [64][65] f32, bfu4 packed store -- 2-way banks both phases = free)
// =====================================================================
__device__ __forceinline__ void t64(const float* __restrict__ src,
                                    bfu* __restrict__ dst,
                                    int C, int r0, int c0, float s,
                                    float (*tile)[65]) {
    const int t  = threadIdx.x;
    const int lr = t >> 4;             // 0..15
    const int lc = (t & 15) * 4;       // 0,4,...,60
    #pragma unroll
    for (int pp = 0; pp < 4; pp++) {
        const float4 v = *(const float4*)(src + (size_t)(r0 + pp*16 + lr) * C + c0 + lc);
        tile[pp*16 + lr][lc + 0] = v.x;
        tile[pp*16 + lr][lc + 1] = v.y;
        tile[pp*16 + lr][lc + 2] = v.z;
        tile[pp*16 + lr][lc + 3] = v.w;
    }
    __syncthreads();
    const int rc = t & 15;             // 4-row chunk along r
    const int cb = t >> 4;             // 0..15
    #pragma unroll
    for (int pp = 0; pp < 4; pp++) {
        const int c = pp*16 + cb;
        bfu4 pk;
        #pragma unroll
        for (int j = 0; j < 4; j++) pk[j] = f2bf(tile[rc*4 + j][c] * s);
        *(bfu4*)(dst + (size_t)(c0 + c) * DM + r0 + rc*4) = pk;
    }
}

// fused Q/K/V weight transpose+convert: grid (2, 32, 48), block 256
__global__ __launch_bounds__(256)
void tcvt_qkv64(const float* __restrict__ WQ, const float* __restrict__ WK,
                const float* __restrict__ WV,
                bfu* __restrict__ WtQ, bfu* __restrict__ WtK, bfu* __restrict__ WtV) {
    __shared__ float tile[64][65];
    const int z = blockIdx.z;
    const int p = z >> 4, h = z & 15;
    const float* src = ((p == 0) ? WQ : (p == 1) ? WK : WV) + (size_t)h * DM * DKH;
    bfu*         dst = ((p == 0) ? WtQ : (p == 1) ? WtK : WtV) + (size_t)h * DKH * DM;
    const float  s   = (p == 0) ? SCALEQ : 1.0f;
    t64(src, dst, DKH, blockIdx.y * 64, blockIdx.x * 64, s, tile);
}

// WO transpose+convert: [2048(hk)][2048(d)] -> [d][hk].  grid (32,32)
__global__ __launch_bounds__(256)
void tcvt_wo64(const float* __restrict__ WO, bfu* __restrict__ WtO) {
    __shared__ float tile[64][65];
    t64(WO, WtO, DM, blockIdx.y * 64, blockIdx.x * 64, 1.0f, tile);
}

// =====================================================================
// 8-phase 256x256 GEMM helpers (T2 st_16x32 swizzle, T3/T4 counted vmcnt,
// T5 setprio).
// =====================================================================
__device__ __forceinline__ void stg_half(const bfu* gbase, bfu* slot,
                                         int wave, int lane, int csw) {
    #pragma unroll
    for (int l = 0; l < 2; l++) {
        const int j = l * 8 + wave;                         // wave-issue id 0..15
        glds16(gbase + (size_t)((j >> 1) * 16 + (lane >> 2)) * DM
                     + (j & 1) * 32 + csw,
               slot + j * 512);
    }
}

__device__ __forceinline__ void ld_b8(bf16x8 (&bv)[4][2], const bfu* slot, int rdo) {
    #pragma unroll
    for (int n = 0; n < 4; n++)
        #pragma unroll
        for (int ks = 0; ks < 2; ks++)
            bv[n][ks] = *(const bf16x8*)&slot[(n * 2 + ks) * 512 + rdo];
}

__device__ __forceinline__ void ld_a8(bf16x8 (&af)[4][2], const bfu* slot, int rdo) {
    #pragma unroll
    for (int m = 0; m < 4; m++)
        #pragma unroll
        for (int ks = 0; ks < 2; ks++)
            af[m][ks] = *(const bf16x8*)&slot[(m * 2 + ks) * 512 + rdo];
}

template<int MH, int NHALF>
__device__ __forceinline__ void mfma16(floatx4 (&acc)[8][4],
                                       const bf16x8 (&af)[4][2],
                                       const bf16x8 (&bv)[4][2]) {
    __builtin_amdgcn_s_setprio(1);
    #pragma unroll
    for (int m = 0; m < 4; m++)
        #pragma unroll
        for (int n = 0; n < 2; n++)
            #pragma unroll
            for (int ks = 0; ks < 2; ks++)
                acc[MH*4 + m][NHALF*2 + n] =
                    __builtin_amdgcn_mfma_f32_16x16x32_bf16(
                        af[m][ks], bv[NHALF*2 + n][ks],
                        acc[MH*4 + m][NHALF*2 + n], 0, 0, 0);
    __builtin_amdgcn_s_setprio(0);
}

#define BARW()                                                      \
    __builtin_amdgcn_s_barrier();                                   \
    asm volatile("s_waitcnt lgkmcnt(0)" ::: "memory");              \
    __builtin_amdgcn_sched_barrier(0)

// =====================================================================
// Q+K projection, 256^2 8-phase: grid (16, 16) = EXACTLY 256 blocks
// =====================================================================
__global__ __launch_bounds__(512, 2)
void proj_qk8(const bfu* __restrict__ xb,
              const bfu* __restrict__ WtQ, const bfu* __restrict__ WtK,
              const float* __restrict__ bQ, const float* __restrict__ bK,
              bfu* __restrict__ Qall, bfu* __restrict__ Kall) {
    __shared__ __align__(16) bfu As[2][2][8192];   // [buf][half][128*64]
    __shared__ __align__(16) bfu Bs[2][2][8192];

    const int p = blockIdx.y >> 3;
    const bfu*   Wt   = (p == 0) ? WtQ : WtK;
    const float* bias = (p == 0) ? bQ  : bK;
    const float  bscale = (p == 0) ? SCALEQ : 1.0f;

    const int tid  = threadIdx.x;
    const int lane = tid & 63;
    const int wave = tid >> 6;
    const int lrow = lane & 15;
    const int quad = lane >> 4;
    const int wr   = wave >> 2;            // 0..1 : M half (128 rows)
    const int wc   = wave & 3;             // 0..3 : N quarter (64 cols)
    const size_t m0 = (size_t)blockIdx.x * 256;
    const int    n0 = (int)(blockIdx.y & 7) * 256;

    const int csw = ((lane & 3) * 8) ^ ((lane & 32) ? 16 : 0);
    const int rdo = lrow * 32 + ((quad * 8) ^ ((lrow & 8) ? 16 : 0));

    const bfu* Ab = xb + m0 * DM;
    const bfu* Bb = Wt + (size_t)n0 * DM;

    floatx4 acc[8][4] = {};
    bf16x8 af[4][2], bv[4][2];

#define STAGE_A(tau, h)                                                     \
    if ((tau) < 32) stg_half(Ab + (size_t)((h) * 128) * DM + (tau) * 64,    \
                             &As[(tau) & 1][h][0], wave, lane, csw)
#define STAGE_B(tau, h)                                                     \
    if ((tau) < 32) stg_half(Bb + (size_t)((h) * 128) * DM + (tau) * 64,    \
                             &Bs[(tau) & 1][h][0], wave, lane, csw)

    // ---- prologue: 7 half-tiles (K-tile 0 + 3/4 of K-tile 1) ----
    STAGE_B(0, 0); STAGE_B(0, 1); STAGE_A(0, 0); STAGE_A(0, 1);
    STAGE_B(1, 0); STAGE_B(1, 1); STAGE_A(1, 0);
    asm volatile("s_waitcnt vmcnt(6)" ::: "memory");
    __builtin_amdgcn_s_barrier();

    #pragma unroll 1
    for (int i = 0; i < 16; i++) {
        const int t0 = 2 * i;
        // ======== K-tile t0 (buf 0) ========
        ld_b8(bv, &Bs[0][wc >> 1][(wc & 1) * 4096], rdo);
        ld_a8(af, &As[0][wr][0], rdo);
        STAGE_A(t0 + 1, 1);
        BARW();
        mfma16<0, 0>(acc, af, bv);
        __builtin_amdgcn_s_barrier();
        STAGE_B(t0 + 2, 0);
        BARW();
        mfma16<0, 1>(acc, af, bv);
        __builtin_amdgcn_s_barrier();
        ld_a8(af, &As[0][wr][4096], rdo);
        STAGE_B(t0 + 2, 1);
        BARW();
        mfma16<1, 0>(acc, af, bv);
        __builtin_amdgcn_s_barrier();
        STAGE_A(t0 + 2, 0);
        BARW();
        mfma16<1, 1>(acc, af, bv);
        if (i == 15) asm volatile("s_waitcnt vmcnt(0)" ::: "memory");
        else         asm volatile("s_waitcnt vmcnt(6)" ::: "memory");
        __builtin_amdgcn_s_barrier();
        // ======== K-tile t0+1 (buf 1) ========
        ld_b8(bv, &Bs[1][wc >> 1][(wc & 1) * 4096], rdo);
        ld_a8(af, &As[1][wr][0], rdo);
        STAGE_A(t0 + 2, 1);
        BARW();
        mfma16<0, 0>(acc, af, bv);
        __builtin_amdgcn_s_barrier();
        STAGE_B(t0 + 3, 0);
        BARW();
        mfma16<0, 1>(acc, af, bv);
        __builtin_amdgcn_s_barrier();
        ld_a8(af, &As[1][wr][4096], rdo);
        STAGE_B(t0 + 3, 1);
        BARW();
        mfma16<1, 0>(acc, af, bv);
        __builtin_amdgcn_s_barrier();
        STAGE_A(t0 + 3, 0);
        BARW();
        mfma16<1, 1>(acc, af, bv);
        if (i < 15) asm volatile("s_waitcnt vmcnt(6)" ::: "memory");
        __builtin_amdgcn_s_barrier();
    }
#undef STAGE_A
#undef STAGE_B

    // ---- epilogue (C/D: col = lane&15 -> n, row = quad*4+r -> m) ----
    bfu* Out = (p == 0) ? Qall : Kall;
    #pragma unroll
    for (int m = 0; m < 8; m++) {
        #pragma unroll
        for (int n = 0; n < 4; n++) {
            const int gn = n0 + wc * 64 + n * 16 + lrow;
            const float bvv = bias[gn] * bscale;
            #pragma unroll
            for (int r = 0; r < 4; r++) {
                const size_t gm = m0 + wr * 128 + m * 16 + quad * 4 + r;
                Out[gm * DM + gn] = f2bf(acc[m][n][r] + bvv);
            }
        }
    }
}

// =====================================================================
// V projection, 2-phase 128^2 (m97-style): Vt[b][h][dk][s] epilogue.
// grid (32,16), block 256
// =====================================================================
__global__ __launch_bounds__(256)
void proj_v(const bfu* __restrict__ xb, const bfu* __restrict__ WtV,
            const float* __restrict__ bV, bfu* __restrict__ Vt) {
    __shared__ bfu As[128 * 32];
    __shared__ bfu Bs[128 * 32];
    const int tid  = threadIdx.x;
    const int lane = tid & 63;
    const int wave = tid >> 6;
    const int lrow = lane & 15;
    const int quad = lane >> 4;
    const int mw = (wave & 1) * 64;
    const int nw = (wave >> 1) * 64;
    const size_t m0 = (size_t)blockIdx.x * 128;
    const size_t n0 = (size_t)blockIdx.y * 128;
    const int rowb = lane >> 2;          // 16-row group offset
    const int colb = (lane & 3) * 8;     // k-offset (elems)

    floatx4 acc[4][4] = {};

    for (int k0 = 0; k0 < DM; k0 += 32) {
        __syncthreads();
        #pragma unroll
        for (int i = 0; i < 2; i++) {
            const int rg = wave * 2 + i;    // 0..7 : 16-row groups
            glds16(xb  + (m0 + rg*16 + rowb) * DM + k0 + colb, &As[rg * 512]);
            glds16(WtV + (n0 + rg*16 + rowb) * DM + k0 + colb, &Bs[rg * 512]);
        }
        __syncthreads();
        bf16x8 af[4], bfr[4];
        #pragma unroll
        for (int t = 0; t < 4; t++) {
            af[t]  = *(const bf16x8*)&As[(mw + t*16 + lrow) * 32 + quad * 8];
            bfr[t] = *(const bf16x8*)&Bs[(nw + t*16 + lrow) * 32 + quad * 8];
        }
        #pragma unroll
        for (int mt = 0; mt < 4; mt++)
            #pragma unroll
            for (int nt = 0; nt < 4; nt++)
                acc[mt][nt] = __builtin_amdgcn_mfma_f32_16x16x32_bf16(
                                  af[mt], bfr[nt], acc[mt][nt], 0, 0, 0);
    }

    // transposed epilogue -> Vt[b][h][dk][s]
    #pragma unroll
    for (int mt = 0; mt < 4; mt++) {
        #pragma unroll
        for (int nt = 0; nt < 4; nt++) {
            const int nl = (int)n0 + nw + nt*16 + lrow;
            const float bvv = bV[nl];
            const size_t gm0 = m0 + mw + mt*16 + quad*4;   // 4 consecutive s rows
            const int b = (int)(gm0 >> 11), s = (int)(gm0 & 2047);
            bfu4 pk;
            #pragma unroll
            for (int r = 0; r < 4; r++) pk[r] = f2bf(acc[mt][nt][r] + bvv);
            *(bfu4*)&Vt[((size_t)(b * NH + (nl >> 7)) * DKH + (nl & 127)) * SEQ + s] = pk;
        }
    }
}

// =====================================================================
// causal flash attention, 64-key tiles, swapped QK^T, swizzled K/V LDS.
// Single-buffer (R5 structure: 42 KB LDS, 3 blocks/CU -- dbuf's 73 KB
// cost a block/CU and regressed).  NEW: (1) masked tail split -- tiles
// it<qt are provably mask-free (s0+63 < qg for every lane), only the
// diagonal tile runs cndmask; (2) scores pre-scaled by log2(e) in W_Q
// -> hardware exp2, deleting 16 v_mul/tile; (3) T5 setprio around MFMA
// clusters (3 independent blocks/CU = m191's +4-7% regime).
// grid (32 hb, 32 qt'), block 256
// =====================================================================
__global__ __launch_bounds__(256)
void flash_attn(const bfu* __restrict__ Q, const bfu* __restrict__ K,
                const bfu* __restrict__ Vt, bfu* __restrict__ Z) {
    __shared__ bfu Ks[4][64][32];    // [kc][key][32 k-elems] : 16 KB
    __shared__ bfu Vs[2][128][32];   // [s-half][dk][32 s]    : 16 KB
    __shared__ bfu Ps[4][16][72];    // per wave [q][64 s + 8 pad] : 9 KB

    const int tid  = threadIdx.x;
    const int lane = tid & 63;
    const int wave = tid >> 6;
    const int lrow = lane & 15;
    const int quad = lane >> 4;
    const int hb = blockIdx.x;
    const int h = hb & 15, b = hb >> 4;
    const int qt = 31 - blockIdx.y;            // heavy blocks first
    const int q0w = qt * 64 + wave * 16;
    const int rowb = lane >> 2;
    // stage: inverse-swizzled global col (LDS row = lane>>2 -> row&8 = lane&32)
    const int csw  = ((lane & 3) * 8) ^ ((lane & 32) ? 16 : 0);
    // read: chunk selector XOR (row&8 = lrow&8)
    const int rq0  = (quad * 8) ^ ((lrow & 8) ? 16 : 0);

    const bfu* Qrow = Q + (size_t)(b * SEQ + q0w + lrow) * DM + h * DKH;
    bf16x8 qf[4];
    #pragma unroll
    for (int kc = 0; kc < 4; kc++)
        qf[kc] = *(const bf16x8*)(Qrow + kc*32 + quad*8);

    floatx4 z[8] = {};
    float l_loc = 0.f;
    const int qg = q0w + lrow;                 // this lane's q row (swapped layout)

    const bfu* Kb = K + (size_t)b * SEQ * DM + h * DKH;
    const bfu* Vb = Vt + (size_t)(b * NH + h) * DKH * SEQ;
    const int ntiles = qt + 1;                 // 64-key tiles, causal

    for (int it = 0; it < ntiles; it++) {
        const int s0 = it * 64;
        __syncthreads();                       // prior iter's LDS reads done
        #pragma unroll
        for (int i = 0; i < 8; i++) {
            const int chunk = wave * 8 + i;    // wave-uniform
            if (chunk < 16) {
                const int kc = chunk >> 2, kg = chunk & 3;
                glds16(Kb + (size_t)(s0 + kg*16 + rowb) * DM + kc*32 + csw,
                       &Ks[kc][kg*16][0]);
            } else {
                const int c2 = chunk - 16;
                const int sh = c2 >> 3, dg = c2 & 7;
                glds16(Vb + (size_t)(dg*16 + rowb) * SEQ + s0 + sh*32 + csw,
                       &Vs[sh][dg*16][0]);
            }
        }
        __syncthreads();                       // staged data visible

        // ---- S^T = K Q^T : lane holds S[s=st*16+quad*4+r][q=lrow] ----
        floatx4 sc[4];
        __builtin_amdgcn_s_setprio(1);
        #pragma unroll
        for (int st = 0; st < 4; st++) {
            floatx4 a = {};
            #pragma unroll
            for (int kc = 0; kc < 4; kc++) {
                bf16x8 kf = *(const bf16x8*)&Ks[kc][st*16 + lrow][rq0];
                a = __builtin_amdgcn_mfma_f32_16x16x32_bf16(kf, qf[kc], a, 0, 0, 0);
            }
            sc[st] = a;
        }
        __builtin_amdgcn_s_setprio(0);

        // ---- softmax: branch-free for interior tiles, masks on diagonal ----
        if (it + 1 < ntiles) {
            #pragma unroll
            for (int st = 0; st < 4; st++) {
                const float p0 = ex2(sc[st][0]);
                const float p1 = ex2(sc[st][1]);
                const float p2 = ex2(sc[st][2]);
                const float p3 = ex2(sc[st][3]);
                l_loc += (p0 + p1) + (p2 + p3);
                u32x2 pk;
                pk[0] = (unsigned)f2bf(p0) | ((unsigned)f2bf(p1) << 16);
                pk[1] = (unsigned)f2bf(p2) | ((unsigned)f2bf(p3) << 16);
                *(u32x2*)&Ps[wave][lrow][st*16 + quad*4] = pk;
            }
        } else {
            #pragma unroll
            for (int st = 0; st < 4; st++) {
                const int sbase = s0 + st*16 + quad*4;
                const float p0 = (sbase + 0 <= qg) ? ex2(sc[st][0]) : 0.f;
                const float p1 = (sbase + 1 <= qg) ? ex2(sc[st][1]) : 0.f;
                const float p2 = (sbase + 2 <= qg) ? ex2(sc[st][2]) : 0.f;
                const float p3 = (sbase + 3 <= qg) ? ex2(sc[st][3]) : 0.f;
                l_loc += (p0 + p1) + (p2 + p3);
                u32x2 pk;
                pk[0] = (unsigned)f2bf(p0) | ((unsigned)f2bf(p1) << 16);
                pk[1] = (unsigned)f2bf(p2) | ((unsigned)f2bf(p3) << 16);
                *(u32x2*)&Ps[wave][lrow][st*16 + quad*4] = pk;
            }
        }

        // ---- O += P V ----
        bf16x8 pf0 = *(const bf16x8*)&Ps[wave][lrow][quad*8];
        bf16x8 pf1 = *(const bf16x8*)&Ps[wave][lrow][32 + quad*8];
        __builtin_amdgcn_s_setprio(1);
        #pragma unroll
        for (int dt = 0; dt < 8; dt++) {
            bf16x8 v0 = *(const bf16x8*)&Vs[0][dt*16 + lrow][rq0];
            z[dt] = __builtin_amdgcn_mfma_f32_16x16x32_bf16(pf0, v0, z[dt], 0, 0, 0);
            bf16x8 v1 = *(const bf16x8*)&Vs[1][dt*16 + lrow][rq0];
            z[dt] = __builtin_amdgcn_mfma_f32_16x16x32_bf16(pf1, v1, z[dt], 0, 0, 0);
        }
        __builtin_amdgcn_s_setprio(0);
    }

    // ---- final l reduce + normalize + store ----
    float L = l_loc;
    L += __shfl_xor(L, 16);
    L += __shfl_xor(L, 32);
    float inv[4];
    #pragma unroll
    for (int r = 0; r < 4; r++)
        inv[r] = 1.0f / __shfl(L, quad*4 + r, 64);
    #pragma unroll
    for (int dt = 0; dt < 8; dt++) {
        #pragma unroll
        for (int r = 0; r < 4; r++) {
            const int qq = q0w + quad*4 + r;
            const int dk = dt*16 + lrow;
            Z[(size_t)(b * SEQ + qq) * DM + h * DKH + dk] = f2bf(z[dt][r] * inv[r]);
        }
    }
}

// =====================================================================
// output projection (m97-style): out_f32 = Zb * WtO^T + bO — unchanged
// =====================================================================
__global__ __launch_bounds__(256)
void out_gemm(const bfu* __restrict__ Zb, const bfu* __restrict__ WtO,
              const float* __restrict__ bO, float* out) {
    __shared__ bfu As[128 * 32];
    __shared__ bfu Bs[128 * 32];
    const int tid  = threadIdx.x;
    const int lane = tid & 63;
    const int wave = tid >> 6;
    const int lrow = lane & 15;
    const int quad = lane >> 4;
    const int mw = (wave & 1) * 64;
    const int nw = (wave >> 1) * 64;
    const size_t m0 = (size_t)blockIdx.x * 128;
    const size_t n0 = (size_t)blockIdx.y * 128;
    const int rowb = lane >> 2, colb = (lane & 3) * 8;

    floatx4 acc[4][4] = {};

    for (int k0 = 0; k0 < DM; k0 += 32) {
        __syncthreads();
        #pragma unroll
        for (int i = 0; i < 2; i++) {
            const int rg = wave * 2 + i;
            glds16(Zb  + (m0 + rg*16 + rowb) * DM + k0 + colb, &As[rg * 512]);
            glds16(WtO + (n0 + rg*16 + rowb) * DM + k0 + colb, &Bs[rg * 512]);
        }
        __syncthreads();
        bf16x8 af[4], bfr[4];
        #pragma unroll
        for (int t = 0; t < 4; t++) {
            af[t]  = *(const bf16x8*)&As[(mw + t*16 + lrow) * 32 + quad * 8];
            bfr[t] = *(const bf16x8*)&Bs[(nw + t*16 + lrow) * 32 + quad * 8];
        }
        #pragma unroll
        for (int mt = 0; mt < 4; mt++)
            #pragma unroll
            for (int nt = 0; nt < 4; nt++)
                acc[mt][nt] = __builtin_amdgcn_mfma_f32_16x16x32_bf16(
                                  af[mt], bfr[nt], acc[mt][nt], 0, 0, 0);
    }

    #pragma unroll
    for (int mt = 0; mt < 4; mt++) {
        #pragma unroll
        for (int nt = 0; nt < 4; nt++) {
            const size_t gn = n0 + nw + nt*16 + lrow;
            const float bv = bO[gn];
            #pragma unroll
            for (int r = 0; r < 4; r++) {
                const size_t gm = m0 + mw + mt*16 + quad*4 + r;
                out[gm * DM + gn] = acc[mt][nt][r] + bv;
            }
        }
    }
}

// =====================================================================
extern "C" void kernel_launch(void* const* d_in, const int* in_sizes, int n_in,
                              void* d_out, int out_size, void* d_ws, size_t ws_size,
                              hipStream_t stream) {
    const float* x  = (const float*)d_in[0];
    const float* WQ = (const float*)d_in[1];
    const float* bQ = (const float*)d_in[2];
    const float* WK = (const float*)d_in[3];
    const float* bK = (const float*)d_in[4];
    const float* WV = (const float*)d_in[5];
    const float* bV = (const float*)d_in[6];
    const float* WO = (const float*)d_in[7];
    const float* bO = (const float*)d_in[8];
    float* out = (float*)d_out;
    bfu* ws  = (bfu*)d_ws;
    bfu* dob = (bfu*)d_out;   // d_out doubles as scratch before out_gemm writes it

    // ws (64 MiB = 33.55M bfu):
    //   ws0: Qall [4096][2048]  -> after flash: WtO [2048][2048]
    //   ws1: Kall [4096][2048]
    //   ws2: Vt   [2][16][128][2048]
    //   ws3: WtV (4.19M) -> after proj: Zb [4096][2048]
    // d_out (16.78M bfu) as early scratch:
    //   xb  = dob[0 .. 8.39M)          (bf16 x)
    //   WtQ = dob[8.39M .. 12.58M)
    //   WtK = dob[12.58M .. 16.78M)
    bfu* Qall = ws;
    bfu* Kall = Qall + 8388608;
    bfu* Vt   = Kall + 8388608;
    bfu* Zb   = Vt   + 8388608;
    bfu* WtV  = Zb;                     // dead before flash writes Zb
    bfu* xb   = dob;
    bfu* WtQ  = dob + 8388608;
    bfu* WtK  = dob + 12582912;

    cvt_x<<<8192, 256, 0, stream>>>(x, xb, BATCH * SEQ * DM);

    // vectorized weight transposes (Q scaled by log2e/sqrt(128))
    tcvt_qkv64<<<dim3(2, 32, 48), 256, 0, stream>>>(WQ, WK, WV, WtQ, WtK, WtV);

    // Q+K: one clean 256-block 8-phase round; V: 2-phase 128^2 (512 blocks)
    proj_qk8<<<dim3(16, 16), 512, 0, stream>>>(xb, WtQ, WtK, bQ, bK, Qall, Kall);
    proj_v<<<dim3(32, 16), 256, 0, stream>>>(xb, WtV, bV, Vt);

    flash_attn<<<dim3(32, 32), 256, 0, stream>>>(Qall, Kall, Vt, Zb);

    // Qall dead -> its region becomes WtO (vectorized transpose)
    tcvt_wo64<<<dim3(32, 32), 256, 0, stream>>>(WO, Qall);
    out_gemm<<<dim3(32, 16), 256, 0, stream>>>(Zb, Qall, bO, out);
}